// Round 6
// baseline (271.586 us; speedup 1.0000x reference)
//
#include <hip/hip_runtime.h>

#define BATCH 4
#define N_PER 300
#define IN_DIM 256
#define KEY_DIM 32
#define FH 160
#define FW 160
#define HW (FH * FW)                 // 25600
#define NQ (BATCH * N_PER)           // 1200
#define Q_ELEMS (NQ * KEY_DIM)       // 38400 fp32 in ws: qry_feats [n][c]
#define KWT_ELEMS (IN_DIM * KEY_DIM) // 8192 fp32 in ws: key_w transposed [c][o]

#define QBLOCKS NQ                   // 1200 blocks: one per query row
#define TBLOCKS (KWT_ELEMS / 256)    // 32 transpose blocks
#define PXB 128                      // pixels per block (2 per thread)
#define NQUAR (N_PER / 4)            // 75 queries per wave
#define CQUAR (IN_DIM / 4)           // 64 channels per wave

// ---------------------------------------------------------------------------
// Prep (unchanged — fast since round 1).
// ---------------------------------------------------------------------------
__global__ __launch_bounds__(256) void prep_kernel(
        const float* __restrict__ in_feats,
        const float* __restrict__ qry_w,
        const float* __restrict__ qry_b,
        const float* __restrict__ key_w,
        float* __restrict__ ws) {
    const int bid = blockIdx.x;
    const int t = threadIdx.x;
    if (bid < QBLOCKS) {
        const int n   = bid;
        const int c   = t >> 3;      // 0..31
        const int sub = t & 7;       // 0..7  (k-chunk)
        const float4* __restrict__ f4 =
            (const float4*)(in_feats + n * IN_DIM + sub * 32);
        const float4* __restrict__ w4 =
            (const float4*)(qry_w + c * IN_DIM + sub * 32);
        float a0 = 0.f, a1 = 0.f, a2 = 0.f, a3 = 0.f;
        #pragma unroll
        for (int j = 0; j < 8; ++j) {
            float4 fv = f4[j];
            float4 wv = w4[j];
            a0 += fv.x * wv.x;
            a1 += fv.y * wv.y;
            a2 += fv.z * wv.z;
            a3 += fv.w * wv.w;
        }
        float s = (a0 + a1) + (a2 + a3);
        s += __shfl_xor(s, 1);
        s += __shfl_xor(s, 2);
        s += __shfl_xor(s, 4);
        if (sub == 0) ws[n * KEY_DIM + c] = s + qry_b[c];
    } else {
        const int i = (bid - QBLOCKS) * 256 + t;   // 0..8191
        const int c = i >> 5;                      // 0..255
        const int o = i & 31;                      // 0..31
        ws[Q_ELEMS + i] = key_w[o * IN_DIM + c];   // kwT[c*32 + o]
    }
}

// ---------------------------------------------------------------------------
// Fused main v7: 2 PIXELS PER THREAD to amortize the per-row scalar stall.
//
// Diagnosis (v1-v6 invariant ~26us VALU-issue over 103-125us): q/kwT rows
// ride the scalar path (correct — SGPR operands broadcast for free; any
// VGPR materialization costs 64x RF-delivery), but SMEM returns are
// unordered so every row use sits behind s_waitcnt lgkmcnt(0): ~150-250cy
// K$-miss exposed vs only 64-128cy of covering FMA.  More waves never fixed
// this (v4==v5==v6).
//
// Fix: each thread owns 2 pixels (l and l+64).  Every scalar row now feeds
// 2x the FMAs (128cy/wave per row in ph2, 128cy in ph1), covering most of
// the stall; unroll 2 batches two rows' s_loads per lgkmcnt(0).  Same
// total FLOPs / HBM bytes.  Block = 128 px x 4 waves (c-split + 32KB
// 3-barrier reduce, n-split ph2), grid 200x4 = 800 blocks = 3200 waves.
// ---------------------------------------------------------------------------
__global__ __launch_bounds__(256) void main_kernel(
        const float* __restrict__ feat_map,
        const float* __restrict__ key_b,
        const float* __restrict__ ws,
        float* __restrict__ out) {
    __shared__ float bufA[2][KEY_DIM][PXB];        // 32 KB

    const int t   = threadIdx.x;
    const int l   = t & 63;                                   // lane
    const int w   = __builtin_amdgcn_readfirstlane(t >> 6);   // wave 0..3, SGPR
    const int b   = blockIdx.y;
    const int pix = blockIdx.x * PXB + l;          // second pixel = pix + 64

    const float* __restrict__ fb  =
        feat_map + ((size_t)b * IN_DIM + w * CQUAR) * HW + pix;
    const float* __restrict__ kwT = ws + Q_ELEMS + (w * CQUAR) * KEY_DIM;

    float acc0[KEY_DIM], acc1[KEY_DIM];
    #pragma unroll
    for (int o = 0; o < KEY_DIM; ++o) { acc0[o] = 0.f; acc1[o] = 0.f; }

    // Phase 1: 64 c-iters; per row: 2 coalesced feat loads + 64 FMAs
    // (covers the kwT s_load stall); kwT rows stay scalar.
    #pragma unroll 4
    for (int c = 0; c < CQUAR; ++c) {
        float f0 = fb[(size_t)c * HW];
        float f1 = fb[(size_t)c * HW + 64];
        const float* __restrict__ kr = kwT + c * KEY_DIM;
        #pragma unroll
        for (int o = 0; o < KEY_DIM; ++o) {
            float kv = kr[o];
            acc0[o] += kv * f0;
            acc1[o] += kv * f1;
        }
    }

    // Cross-wave reduce, 32 KB / 3 barriers (v6 scheme, 2 px per thread):
    if (w >= 2) {
        #pragma unroll
        for (int o = 0; o < KEY_DIM; ++o) {
            bufA[w - 2][o][l]      = acc0[o];
            bufA[w - 2][o][l + 64] = acc1[o];
        }
    }
    __syncthreads();
    if (w < 2) {
        #pragma unroll
        for (int o = 0; o < KEY_DIM; ++o) {
            acc0[o] += bufA[w][o][l];
            acc1[o] += bufA[w][o][l + 64];
        }
    }
    if (w == 1) {
        #pragma unroll
        for (int o = 0; o < KEY_DIM; ++o) {
            bufA[1][o][l]      = acc0[o];
            bufA[1][o][l + 64] = acc1[o];
        }
    }
    __syncthreads();
    float key0[KEY_DIM], key1[KEY_DIM];
    if (w == 0) {
        #pragma unroll
        for (int o = 0; o < KEY_DIM; ++o) {
            key0[o] = acc0[o] + bufA[1][o][l]      + key_b[o];
            key1[o] = acc1[o] + bufA[1][o][l + 64] + key_b[o];
            bufA[0][o][l]      = key0[o];
            bufA[0][o][l + 64] = key1[o];
        }
    }
    __syncthreads();
    if (w != 0) {
        #pragma unroll
        for (int o = 0; o < KEY_DIM; ++o) {
            key0[o] = bufA[0][o][l];
            key1[o] = bufA[0][o][l + 64];
        }
    }

    // Phase 2: 75 rows per wave; per row 2 dot-32s (128cy of FMA vs one
    // lgkmcnt(0) stall); unroll 2 batches two rows' s_loads per wait.
    const float* __restrict__ qb =
        ws + ((size_t)b * N_PER + w * NQUAR) * KEY_DIM;
    float* __restrict__ ob =
        out + ((size_t)b * N_PER + (size_t)w * NQUAR) * HW + pix;

    #pragma unroll 2
    for (int n = 0; n < NQUAR; ++n) {
        const float* __restrict__ qn = qb + n * KEY_DIM;
        float a0 = 0.f, a1 = 0.f, c0 = 0.f, c1 = 0.f;
        #pragma unroll
        for (int c2 = 0; c2 < KEY_DIM; c2 += 2) {
            float q0 = qn[c2], q1 = qn[c2 + 1];
            a0 += q0 * key0[c2];
            a1 += q1 * key0[c2 + 1];
            c0 += q0 * key1[c2];
            c1 += q1 * key1[c2 + 1];
        }
        ob[(size_t)n * HW]      = a0 + a1;
        ob[(size_t)n * HW + 64] = c0 + c1;
    }
}

extern "C" void kernel_launch(void* const* d_in, const int* in_sizes, int n_in,
                              void* d_out, int out_size, void* d_ws, size_t ws_size,
                              hipStream_t stream) {
    const float* in_feats = (const float*)d_in[0];  // [1200, 256]
    const float* feat_map = (const float*)d_in[1];  // [4, 256, 160, 160]
    const float* qry_w    = (const float*)d_in[2];  // [32, 256]
    const float* qry_b    = (const float*)d_in[3];  // [32]
    const float* key_w    = (const float*)d_in[4];  // [32, 256]
    const float* key_b    = (const float*)d_in[5];  // [32]
    float* ws  = (float*)d_ws;                      // needs 46592*4 B
    float* out = (float*)d_out;                     // [1200, 160, 160] fp32

    // Prep: 1200 q-blocks + 32 transpose blocks.
    prep_kernel<<<dim3(QBLOCKS + TBLOCKS), dim3(256), 0, stream>>>(
        in_feats, qry_w, qry_b, key_w, ws);

    // Main: 200 pixel-tiles (128 px) x 4 batches = 800 blocks, 3200 waves.
    main_kernel<<<dim3(HW / PXB, BATCH), dim3(256), 0, stream>>>(
        feat_map, key_b, ws, out);
}

// Round 8
// 267.960 us; speedup vs baseline: 1.0135x; 1.0135x over previous
//
#include <hip/hip_runtime.h>

#define BATCH 4
#define N_PER 300
#define IN_DIM 256
#define KEY_DIM 32
#define FH 160
#define FW 160
#define HW (FH * FW)                 // 25600
#define NQ (BATCH * N_PER)           // 1200

#define QBLOCKS NQ                   // 1200 q-row blocks in prep
#define KWBLOCKS 32                  // 8192/256 cvt blocks in prep
#define Q16_HALFS (NQ * KEY_DIM)     // 38400 f16: ws[0..76800 B)
// kw16 [32][256] f16 at byte 76800..93184  (total 93184 B < 186 KB budget)

#define MT 19                        // m-tiles: 304 rows cover N_PER=300
#define STRIPS 2                     // 16-px strips per wave
#define PXBLK 128                    // 4 waves * 2 strips * 16 px

typedef __fp16 half8 __attribute__((ext_vector_type(8)));
typedef __fp16 half2v __attribute__((ext_vector_type(2)));
typedef float f32x4 __attribute__((ext_vector_type(4)));

// ---------------------------------------------------------------------------
// Prep v8: q projection (proven shfl-reduce structure) now stored as f16,
// plus f16 conversion of key_w (row-major [o][d], no transpose needed:
// MFMA A-frags read 8 contiguous k-elements per lane).
// ---------------------------------------------------------------------------
__global__ __launch_bounds__(256) void prep_kernel(
        const float* __restrict__ in_feats,
        const float* __restrict__ qry_w,
        const float* __restrict__ qry_b,
        const float* __restrict__ key_w,
        void* __restrict__ ws) {
    const int bid = blockIdx.x;
    const int t = threadIdx.x;
    _Float16* __restrict__ wh = (_Float16*)ws;
    if (bid < QBLOCKS) {
        const int n   = bid;
        const int c   = t >> 3;      // 0..31
        const int sub = t & 7;       // 0..7  (k-chunk)
        const float4* __restrict__ f4 =
            (const float4*)(in_feats + n * IN_DIM + sub * 32);
        const float4* __restrict__ w4 =
            (const float4*)(qry_w + c * IN_DIM + sub * 32);
        float a0 = 0.f, a1 = 0.f, a2 = 0.f, a3 = 0.f;
        #pragma unroll
        for (int j = 0; j < 8; ++j) {
            float4 fv = f4[j];
            float4 wv = w4[j];
            a0 += fv.x * wv.x;
            a1 += fv.y * wv.y;
            a2 += fv.z * wv.z;
            a3 += fv.w * wv.w;
        }
        float s = (a0 + a1) + (a2 + a3);
        s += __shfl_xor(s, 1);
        s += __shfl_xor(s, 2);
        s += __shfl_xor(s, 4);
        if (sub == 0) wh[n * KEY_DIM + c] = (_Float16)(s + qry_b[c]);
    } else {
        const int i = (bid - QBLOCKS) * 256 + t;   // 0..8191
        wh[Q16_HALFS + i] = (_Float16)key_w[i];    // kw16[o][d] row-major
    }
}

// ---------------------------------------------------------------------------
// Fused main v8 (MFMA): per wave per 16-px strip:
//   phase 1: Kmap(32 x 16px) = kw16(32x256) @ feat(256x16px)   16 MFMAs
//            feat loaded f32 (coalesced, 64 regs preloaded) -> cvt_pkrtz f16
//   epilogue: + key_b; pack f16; wave-private LDS transpose into B-frag
//             layout [px][o] (XOR chunk swizzle, 2-way banks = free)
//   phase 2: out(304 x 16px) = q16(304x32) @ key(32x16px)      19 MFMAs
// q16 (19.4 KB) + kw16 (16 KB) staged in LDS once per block, XOR-swizzled
// so all a-frag ds_read_b128 are 2-way (free). 3.65 GFLOP MFMA total
// (~1.8 us of matrix pipe) -> kernel rides the HBM floor (~28-36 us).
// Fragment facts used (HW-verified in learn_hip): 16x16x32 A/B frag = 8
// CONTIGUOUS k per lane, k=(l>>4)*8+j (m92 refcheck); C/D col=lane&15,
// row=(lane>>4)*4+reg (m89).
// ---------------------------------------------------------------------------
__global__ __launch_bounds__(256) void main_kernel(
        const float* __restrict__ feat_map,
        const float* __restrict__ key_b,
        const void* __restrict__ ws,
        float* __restrict__ out) {
    __shared__ _Float16 lds_q[304 * KEY_DIM];      // 19456 B, swizzled
    __shared__ _Float16 lds_kw[KEY_DIM * IN_DIM];  // 16384 B, swizzled
    __shared__ _Float16 lds_key[4 * 16 * KEY_DIM]; //  4096 B, per-wave keyT

    const int t = threadIdx.x;
    const int b = blockIdx.y;
    const _Float16* __restrict__ q16g  = (const _Float16*)ws;
    const _Float16* __restrict__ kw16g = (const _Float16*)ws + Q16_HALFS;

    // ---- stage kw16: 1024 16-B chunks; swizzle chunk' = ch ^ (o&7)
    #pragma unroll
    for (int it = 0; it < 4; ++it) {
        int idx = it * 256 + t;                    // 0..1023
        int o = idx >> 5, ch = idx & 31;
        uint4 v = *(const uint4*)((const char*)kw16g + o * 512 + ch * 16);
        *(uint4*)((char*)lds_kw + o * 512 + ((ch ^ (o & 7)) << 4)) = v;
    }
    // ---- stage q16: 304 rows x 4 chunks; swizzle ch' = ch ^ ((row>>1)&3)
    #pragma unroll
    for (int it = 0; it < 5; ++it) {
        int idx = it * 256 + t;
        if (idx < 304 * 4) {
            int row = idx >> 2, ch = idx & 3;
            uint4 v = {0u, 0u, 0u, 0u};           // zero-pad rows 300..303
            if (row < N_PER)
                v = *(const uint4*)((const char*)q16g
                        + ((size_t)b * N_PER + row) * 64 + ch * 16);
            *(uint4*)((char*)lds_q + row * 64
                        + ((ch ^ ((row >> 1) & 3)) << 4)) = v;
        }
    }
    __syncthreads();

    const int l    = t & 63;
    const int w    = t >> 6;        // wave 0..3
    const int ln15 = l & 15;        // px-col / m-row within tile
    const int qw   = l >> 4;        // quarter-wave 0..3

    // bias fragments: lane needs key_b[qw*4 + r] (C/D row = qw*4 + r)
    const float4 kb0 = *(const float4*)(key_b + qw * 4);
    const float4 kb1 = *(const float4*)(key_b + 16 + qw * 4);

    const float* __restrict__ fbl =
        feat_map + ((size_t)b * IN_DIM + qw * 8) * HW;

    #pragma unroll 1
    for (int s = 0; s < STRIPS; ++s) {
        const int px = blockIdx.x * PXBLK + w * 32 + s * 16 + ln15;

        // ---- preload feat f32: d = qw*8 + kt*32 + j  (coalesced 64B segs)
        float fr[8][8];
        #pragma unroll
        for (int kt = 0; kt < 8; ++kt)
            #pragma unroll
            for (int j = 0; j < 8; ++j)
                fr[kt][j] = fbl[(size_t)(kt * 32 + j) * HW + px];

        // ---- phase 1: Kmap tiles (o 0..15 and 16..31)
        f32x4 acc0 = {0.f, 0.f, 0.f, 0.f};
        f32x4 acc1 = {0.f, 0.f, 0.f, 0.f};
        #pragma unroll
        for (int kt = 0; kt < 8; ++kt) {
            union { half2v p[4]; half8 v; } bf;
            #pragma unroll
            for (int i = 0; i < 4; ++i)
                bf.p[i] = __builtin_amdgcn_cvt_pkrtz(fr[kt][2 * i],
                                                     fr[kt][2 * i + 1]);
            const int o0 = ln15, o1 = 16 + ln15;
            half8 a0 = *(const half8*)((const char*)lds_kw + o0 * 512
                            + (((kt * 4 + qw) ^ (o0 & 7)) << 4));
            half8 a1 = *(const half8*)((const char*)lds_kw + o1 * 512
                            + (((kt * 4 + qw) ^ (o1 & 7)) << 4));
            acc0 = __builtin_amdgcn_mfma_f32_16x16x32_f16(a0, bf.v, acc0, 0, 0, 0);
            acc1 = __builtin_amdgcn_mfma_f32_16x16x32_f16(a1, bf.v, acc1, 0, 0, 0);
        }

        // ---- epilogue: +bias, pack f16, write keyT [px][o] (swizzled)
        {
            union { half2v p[2]; uint2 u; } k0, k1;
            k0.p[0] = __builtin_amdgcn_cvt_pkrtz(acc0[0] + kb0.x, acc0[1] + kb0.y);
            k0.p[1] = __builtin_amdgcn_cvt_pkrtz(acc0[2] + kb0.z, acc0[3] + kb0.w);
            k1.p[0] = __builtin_amdgcn_cvt_pkrtz(acc1[0] + kb1.x, acc1[1] + kb1.y);
            k1.p[1] = __builtin_amdgcn_cvt_pkrtz(acc1[2] + kb1.z, acc1[3] + kb1.w);
            char* kbase = (char*)lds_key + w * 1024 + ln15 * 64;
            const int half_sel = (qw & 1) * 8;
            const int sw  = (ln15 >> 1) & 3;
            const int ch0 = (qw >> 1);            // o = qw*4..qw*4+3
            const int ch1 = 2 + (qw >> 1);        // o+16
            *(uint2*)(kbase + ((ch0 ^ sw) << 4) + half_sel) = k0.u;
            *(uint2*)(kbase + ((ch1 ^ sw) << 4) + half_sel) = k1.u;
        }
        // wave-private region: same-wave DS ordering + compiler lgkmcnt

        // ---- phase 2: 19 m-tiles x (K=32)
        half8 bkey = *(const half8*)((const char*)lds_key + w * 1024
                        + ln15 * 64 + ((qw ^ ((ln15 >> 1) & 3)) << 4));
        f32x4 acc2[MT];
        #pragma unroll
        for (int mt = 0; mt < MT; ++mt)
            acc2[mt] = (f32x4){0.f, 0.f, 0.f, 0.f};
        #pragma unroll
        for (int mt = 0; mt < MT; ++mt) {
            const int row = mt * 16 + ln15;
            half8 aq = *(const half8*)((const char*)lds_q + row * 64
                            + ((qw ^ ((row >> 1) & 3)) << 4));
            acc2[mt] = __builtin_amdgcn_mfma_f32_16x16x32_f16(aq, bkey,
                                                              acc2[mt], 0, 0, 0);
        }

        // ---- store: D[row=m][col=px]; guard only the tail tile rows
        float* __restrict__ ob = out + (size_t)b * N_PER * HW + px;
        #pragma unroll
        for (int mt = 0; mt < MT; ++mt) {
            #pragma unroll
            for (int r = 0; r < 4; ++r) {
                const int m = mt * 16 + qw * 4 + r;
                if (mt < 18 || m < N_PER)
                    ob[(size_t)m * HW] = acc2[mt][r];
            }
        }
    }
}

extern "C" void kernel_launch(void* const* d_in, const int* in_sizes, int n_in,
                              void* d_out, int out_size, void* d_ws, size_t ws_size,
                              hipStream_t stream) {
    const float* in_feats = (const float*)d_in[0];  // [1200, 256]
    const float* feat_map = (const float*)d_in[1];  // [4, 256, 160, 160]
    const float* qry_w    = (const float*)d_in[2];  // [32, 256]
    const float* qry_b    = (const float*)d_in[3];  // [32]
    const float* key_w    = (const float*)d_in[4];  // [32, 256]
    const float* key_b    = (const float*)d_in[5];  // [32]
    float* out = (float*)d_out;                     // [1200, 160, 160] fp32

    // Prep: 1200 q-blocks + 32 key_w-cvt blocks.  ws use: 93184 B.
    prep_kernel<<<dim3(QBLOCKS + KWBLOCKS), dim3(256), 0, stream>>>(
        in_feats, qry_w, qry_b, key_w, d_ws);

    // Main: 200 px-tiles (128 px) x 4 batches = 800 blocks, 3200 waves.
    main_kernel<<<dim3(HW / PXBLK, BATCH), dim3(256), 0, stream>>>(
        feat_map, key_b, d_ws, out);
}